// Round 1
// baseline (239.935 us; speedup 1.0000x reference)
//
#include <hip/hip_runtime.h>

// SocialPooling on MI355X — round 1: correct fused baseline.
// Inputs (dict order): 0 h_states (1,N,64) f32, 1 seq_start_end (256,2) i32,
// 2 end_pos (N,2) f32, 3 W (4096,64) f32, 4 b (64,) f32, 5 gamma (64,) f32,
// 6 beta (64,) f32.  Output: (N,64) f32, N = 16384.
// seq_start_end is provably uniform (reference only uses N//nseq) -> base = s*64.

#define NSEQ 256
#define NPED 64
#define NTOT (NSEQ * NPED)
#define HD 64
#define EPSV 1e-5f

// Kernel 1: one 64-thread block per anchor. Lane t owns output column t.
// x[i,t] = b[t] + sum over valid j of sum_k h[j,k] * W[(g*64+k)*64 + t]
__global__ __launch_bounds__(64) void sp_pool_matvec(
    const float* __restrict__ h, const float* __restrict__ pos,
    const float* __restrict__ W, const float* __restrict__ bvec,
    float* __restrict__ X)
{
    const int bi   = blockIdx.x;
    const int s    = bi >> 6;       // sequence
    const int i    = bi & 63;       // anchor within sequence
    const int base = s * NPED;
    const int t    = threadIdx.x;   // output column

    __shared__ float px[NPED], py[NPED];
    px[t] = pos[(base + t) * 2 + 0];
    py[t] = pos[(base + t) * 2 + 1];
    __syncthreads();

    const float ax = px[i], ay = py[i];
    const float tlx = ax - 1.0f, tly = ay + 1.0f;
    const float brx = ax + 1.0f, bry = ay - 1.0f;

    float acc = 0.0f;
    for (int j = 0; j < NPED; ++j) {
        if (j == i) continue;                       // diag excluded
        const float ox = px[j], oy = py[j];
        // reference: oob = ox>=br_x | ox<=tl_x | oy>=tl_y | oy<=br_y
        const bool oob = (ox >= brx) | (ox <= tlx) | (oy >= tly) | (oy <= bry);
        if (oob) continue;                          // wave-uniform branch
        // reference: floor((ox-tl_x)/NS*GRID), trunc-to-int, clip 0..63
        const float cx = floorf((ox - tlx) / 2.0f * 8.0f);
        const float cy = floorf((tly - oy) / 2.0f * 8.0f);
        int g = (int)(cx + cy * 8.0f);
        g = g < 0 ? 0 : (g > 63 ? 63 : g);

        const float* __restrict__ wp = W + g * (64 * 64) + t;  // lane-coalesced
        const float* __restrict__ hp = h + (base + j) * HD;    // wave-uniform
        #pragma unroll 16
        for (int k = 0; k < 64; ++k)
            acc = fmaf(hp[k], wp[k * 64], acc);
    }
    X[(base + i) * HD + t] = acc + bvec[t];
}

// Kernel 2: per-column sum & sumsq over all N rows. 64 blocks x 256 threads.
// stats[0..63] = sum, stats[64..127] = sumsq (pre-zeroed via hipMemsetAsync).
__global__ __launch_bounds__(256) void sp_colstats(
    const float* __restrict__ X, float* __restrict__ stats)
{
    const int w    = threadIdx.x >> 6;
    const int lane = threadIdx.x & 63;
    float s = 0.0f, s2 = 0.0f;
    const int rbase = blockIdx.x * 256 + w * 64;
    for (int r0 = 0; r0 < 64; ++r0) {
        const float v = X[(rbase + r0) * HD + lane];  // coalesced 256B/wave
        s += v;
        s2 += v * v;
    }
    __shared__ float red[2][4][64];
    red[0][w][lane] = s;
    red[1][w][lane] = s2;
    __syncthreads();
    if (w == 0) {
        const float a  = red[0][0][lane] + red[0][1][lane] + red[0][2][lane] + red[0][3][lane];
        const float a2 = red[1][0][lane] + red[1][1][lane] + red[1][2][lane] + red[1][3][lane];
        atomicAdd(&stats[lane], a);
        atomicAdd(&stats[64 + lane], a2);
    }
}

// Kernel 3: in-place normalize + affine + ReLU.
__global__ __launch_bounds__(256) void sp_norm_relu(
    float* __restrict__ X, const float* __restrict__ stats,
    const float* __restrict__ gamma, const float* __restrict__ beta)
{
    const int idx = blockIdx.x * 256 + threadIdx.x;
    const int c   = idx & 63;
    const float inv_n = 1.0f / (float)NTOT;
    const float mu  = stats[c] * inv_n;
    const float var = stats[64 + c] * inv_n - mu * mu;
    const float v = (X[idx] - mu) / sqrtf(var + EPSV) * gamma[c] + beta[c];
    X[idx] = fmaxf(v, 0.0f);
}

extern "C" void kernel_launch(void* const* d_in, const int* in_sizes, int n_in,
                              void* d_out, int out_size, void* d_ws, size_t ws_size,
                              hipStream_t stream)
{
    const float* h     = (const float*)d_in[0];
    // d_in[1] = seq_start_end (int32) — provably uniform, unused
    const float* pos   = (const float*)d_in[2];
    const float* W     = (const float*)d_in[3];
    const float* bvec  = (const float*)d_in[4];
    const float* gamma = (const float*)d_in[5];
    const float* beta  = (const float*)d_in[6];

    float* X     = (float*)d_out;   // reuse output buffer as x scratch (N*64 f32)
    float* stats = (float*)d_ws;    // 128 floats: sum + sumsq (poisoned -> zero it)

    hipMemsetAsync(stats, 0, 128 * sizeof(float), stream);
    sp_pool_matvec<<<NTOT, 64, 0, stream>>>(h, pos, W, bvec, X);
    sp_colstats<<<64, 256, 0, stream>>>(X, stats);
    sp_norm_relu<<<(NTOT * HD) / 256, 256, 0, stream>>>(X, stats, gamma, beta);
}

// Round 3
// 129.349 us; speedup vs baseline: 1.8549x; 1.8549x over previous
//
#include <hip/hip_runtime.h>
#include <hip/hip_bf16.h>

// SocialPooling round 3: MFMA formulation, 4 plain launches (no cooperative, no atomics).
// K0: W (4096x64 f32) -> Wt bf16 [g][col][k]   (d_ws)
// K1: per-sequence block: pool pairs per cell, X_s = sum_g P_g @ W_g via 16x16x32 bf16
//     MFMA (full 64x64 acc in VGPRs per wave, 16 cells/wave), LDS cross-wave combine,
//     write X+bias, emit per-block column sum/sumsq partials.
// K2: reduce partials -> stats[128]. K3: normalize+affine+ReLU in place.

#define NSEQ 256
#define NPED 64
#define HD   64
#define NTOT (NSEQ*NPED)
#define EPSV 1e-5f

typedef __attribute__((ext_vector_type(8))) short short8;
typedef __attribute__((ext_vector_type(4))) float f32x4;
typedef unsigned short ushort_t;

__device__ __forceinline__ ushort_t f2b(float f) {
    __hip_bfloat16 h = __float2bfloat16(f);                 // RNE
    return *reinterpret_cast<ushort_t*>(&h);
}
__device__ __forceinline__ float b2f(ushort_t u) {
    return __uint_as_float(((unsigned)u) << 16);
}

// ---------------- K0: transpose one W cell per block ----------------
__global__ __launch_bounds__(256) void sp_transpose(
    const float* __restrict__ W, short* __restrict__ Wt)
{
    __shared__ __align__(16) float Tl[64*68];               // [k][t], pad 68
    const int b = blockIdx.x;                               // cell g
    const int tid = threadIdx.x;
    const float* wg = W + (size_t)b*4096;
    for (int m = 0; m < 4; ++m) {
        int c = m*256 + tid;                                // 1024 f32x4 chunks
        int k = c >> 4, t0 = (c & 15)*4;
        *(f32x4*)(Tl + k*68 + t0) = *(const f32x4*)(wg + k*64 + t0);
    }
    __syncthreads();
    for (int m = 0; m < 2; ++m) {
        int q = m*256 + tid;                                // 512 chunks of 8 bf16
        int col = q >> 3, k0 = (q & 7)*8;
        short8 o;
        #pragma unroll
        for (int i2 = 0; i2 < 8; ++i2)
            o[i2] = (short)f2b(Tl[(k0 + i2)*68 + col]);
        *(short8*)(Wt + ((size_t)(b*64 + col)*64 + k0)) = o; // Wt[g][col][k], 16B coalesced
    }
}

// ---------------- K1: main ----------------
// LDS carve (bytes):
#define SM_HS    0          // u16 Hs[64][72]                    9216
#define SM_P     9216       // u16 P[4][64*72] 36864 ; alias f32 Xs[64][68] 17408
#define SM_PAIR  46080      // u16 prs[4032] 8064   ; alias f32 red[2][4][64] 2048
#define SM_POS   54144      // f32 px[64], py[64]                512
#define SM_CNT   54656      // u32 cnt[64], off[64], woff[64]    768
#define SM_TOTAL 55424

__global__ __launch_bounds__(256) void sp_main(
    const float* __restrict__ h, const float* __restrict__ pos,
    const short* __restrict__ Wt, const float* __restrict__ bvec,
    float* __restrict__ X, float* __restrict__ partials)
{
    __shared__ __align__(16) char smem[SM_TOTAL];
    ushort_t* Hs   = (ushort_t*)(smem + SM_HS);
    ushort_t* prs  = (ushort_t*)(smem + SM_PAIR);
    float*    px   = (float*)(smem + SM_POS);
    float*    py   = px + 64;
    unsigned* cnt  = (unsigned*)(smem + SM_CNT);
    unsigned* off  = cnt + 64;
    unsigned* woff = off + 64;

    const int b    = blockIdx.x;        // sequence
    const int base = b * NPED;
    const int tid  = threadIdx.x;
    const int lane = tid & 63, w = tid >> 6;
    const int ln15 = lane & 15, ln4 = lane >> 4;
    ushort_t* Pw = (ushort_t*)(smem + SM_P) + w*(64*72);    // wave-private bf16 P [64][72]

    if (tid < 64) {
        px[tid] = pos[(base + tid)*2];
        py[tid] = pos[(base + tid)*2 + 1];
        cnt[tid] = 0;
    }
    for (int m = 0; m < 4; ++m) {                           // stage H -> bf16 [64][72]
        int c = m*256 + tid;
        int j = c >> 4, t0 = (c & 15)*4;
        f32x4 v = *(const f32x4*)(h + (size_t)(base + j)*64 + t0);
        Hs[j*72 + t0 + 0] = f2b(v[0]);
        Hs[j*72 + t0 + 1] = f2b(v[1]);
        Hs[j*72 + t0 + 2] = f2b(v[2]);
        Hs[j*72 + t0 + 3] = f2b(v[3]);
    }
    __syncthreads();

    // pass A: count valid pairs per cell (identical math to the R1-passing kernel)
    for (int m = 0; m < 16; ++m) {
        int p = m*256 + tid;
        int i = p >> 6, j = p & 63;
        if (i == j) continue;
        float ax = px[i], ay = py[i], ox = px[j], oy = py[j];
        float tlx = ax - 1.0f, tly = ay + 1.0f, brx = ax + 1.0f, bry = ay - 1.0f;
        bool oob = (ox >= brx) | (ox <= tlx) | (oy >= tly) | (oy <= bry);
        if (oob) continue;
        int g = (int)(floorf((ox - tlx)*4.0f) + floorf((tly - oy)*4.0f)*8.0f);
        g = g < 0 ? 0 : (g > 63 ? 63 : g);
        atomicAdd(&cnt[g], 1u);
    }
    __syncthreads();
    if (tid == 0) {
        unsigned a0 = 0;
        for (int g2 = 0; g2 < 64; ++g2) { off[g2] = a0; woff[g2] = a0; a0 += cnt[g2]; }
    }
    __syncthreads();
    // pass B: scatter (i<<6|j) grouped by cell
    for (int m = 0; m < 16; ++m) {
        int p = m*256 + tid;
        int i = p >> 6, j = p & 63;
        if (i == j) continue;
        float ax = px[i], ay = py[i], ox = px[j], oy = py[j];
        float tlx = ax - 1.0f, tly = ay + 1.0f, brx = ax + 1.0f, bry = ay - 1.0f;
        bool oob = (ox >= brx) | (ox <= tlx) | (oy >= tly) | (oy <= bry);
        if (oob) continue;
        int g = (int)(floorf((ox - tlx)*4.0f) + floorf((tly - oy)*4.0f)*8.0f);
        g = g < 0 ? 0 : (g > 63 ? 63 : g);
        unsigned slot = atomicAdd(&woff[g], 1u);
        prs[slot] = (ushort_t)((i << 6) | j);
    }
    __syncthreads();

    // per-wave: 16 cells, full 64x64 X_s partial in regs
    f32x4 acc[4][4];
    #pragma unroll
    for (int mt = 0; mt < 4; ++mt)
        #pragma unroll
        for (int nt = 0; nt < 4; ++nt) acc[mt][nt] = (f32x4){0.f,0.f,0.f,0.f};

    for (int c = 0; c < 16; ++c) {
        const int g = w*16 + c;
        const int n = (int)cnt[g];
        if (n == 0) continue;
        // B-frags: Wt[g][col][k]; col = nt*16+ln15, k = kt*32 + ln4*8 + 0..7
        short8 bf[2][4];
        const short* wt = Wt + (size_t)g*4096;
        #pragma unroll
        for (int kt = 0; kt < 2; ++kt)
            #pragma unroll
            for (int nt = 0; nt < 4; ++nt)
                bf[kt][nt] = *(const short8*)(wt + (nt*16 + ln15)*64 + kt*32 + ln4*8);
        // zero wave-private P (144 B/lane, contiguous)
        {
            char* pz = (char*)Pw + lane*144;
            f32x4 z = {0.f,0.f,0.f,0.f};
            #pragma unroll
            for (int i2 = 0; i2 < 9; ++i2) *(f32x4*)(pz + i2*16) = z;
        }
        // build P: row i += h[j]; lane = k (u16 RMW, 2 lanes/bank = free)
        const int o0 = (int)off[g];
        for (int e = 0; e < n; ++e) {
            unsigned pr = prs[o0 + e];                       // wave-uniform broadcast
            int i = (int)(pr >> 6), j = (int)(pr & 63);
            float hv = b2f(Hs[j*72 + lane]);
            ushort_t* pp = &Pw[i*72 + lane];
            *pp = f2b(b2f(*pp) + hv);
        }
        // MFMA: acc += P @ W_g ; A[m=ln15][k=ln4*8+j] per m89-verified layouts
        #pragma unroll
        for (int kt = 0; kt < 2; ++kt)
            #pragma unroll
            for (int mt = 0; mt < 4; ++mt) {
                short8 af = *(const short8*)(Pw + (mt*16 + ln15)*72 + kt*32 + ln4*8);
                #pragma unroll
                for (int nt = 0; nt < 4; ++nt)
                    acc[mt][nt] = __builtin_amdgcn_mfma_f32_16x16x32_bf16(af, bf[kt][nt], acc[mt][nt], 0, 0, 0);
            }
    }
    __syncthreads();                                        // all waves done with P region

    // cross-wave combine into Xs [64][68] f32 (aliases P region)
    float* Xs = (float*)(smem + SM_P);
    for (int wv = 0; wv < 4; ++wv) {
        if (w == wv) {
            #pragma unroll
            for (int mt = 0; mt < 4; ++mt)
                #pragma unroll
                for (int nt = 0; nt < 4; ++nt)
                    #pragma unroll
                    for (int rr = 0; rr < 4; ++rr) {
                        int row = mt*16 + ln4*4 + rr;       // C/D: col=lane&15, row=(lane>>4)*4+reg [m89/m91]
                        int col = nt*16 + ln15;
                        if (wv == 0) Xs[row*68 + col]  = acc[mt][nt][rr];
                        else         Xs[row*68 + col] += acc[mt][nt][rr];
                    }
        }
        __syncthreads();
    }

    // write X + bias (coalesced 16B/lane)
    {
        const int row = tid >> 2, c0 = (tid & 3)*16;
        float* xg = X + (size_t)(base + row)*64 + c0;
        #pragma unroll
        for (int q = 0; q < 4; ++q) {
            f32x4 v;
            #pragma unroll
            for (int u = 0; u < 4; ++u)
                v[u] = Xs[row*68 + c0 + q*4 + u] + bvec[c0 + q*4 + u];
            *(f32x4*)(xg + q*4) = v;
        }
    }

    // per-block column sum / sumsq (with bias), reduce across 4 row-groups
    {
        const int col = tid & 63, rg = tid >> 6;
        const float bc = bvec[col];
        float s1 = 0.f, s2 = 0.f;
        for (int ii = 0; ii < 16; ++ii) {
            float v = Xs[(rg*16 + ii)*68 + col] + bc;
            s1 += v; s2 += v*v;
        }
        float* red = (float*)(smem + SM_PAIR);              // [2][4][64], aliases prs (done)
        red[w*64 + col]       = s1;
        red[256 + w*64 + col] = s2;
        __syncthreads();
        if (tid < 128) {
            int half = tid >> 6, c2 = tid & 63;
            const float* r0 = red + half*256;
            float v = r0[c2] + r0[64 + c2] + r0[128 + c2] + r0[192 + c2];
            partials[(size_t)(half*64 + c2)*NSEQ + b] = v;  // partials[slot][block]
        }
    }
}

// ---------------- K2: reduce partials[128][256] -> stats[128] ----------------
__global__ __launch_bounds__(64) void sp_reduce(
    const float* __restrict__ partials, float* __restrict__ stats)
{
    const int slot = blockIdx.x;
    const int lane = threadIdx.x;
    const float* p = partials + (size_t)slot*NSEQ;
    float v = p[lane] + p[64 + lane] + p[128 + lane] + p[192 + lane];
    #pragma unroll
    for (int o = 32; o > 0; o >>= 1) v += __shfl_down(v, o);
    if (lane == 0) stats[slot] = v;
}

// ---------------- K3: normalize + affine + ReLU in place ----------------
__global__ __launch_bounds__(256) void sp_norm(
    float* __restrict__ X, const float* __restrict__ stats,
    const float* __restrict__ gamma, const float* __restrict__ beta)
{
    const int idx = blockIdx.x*256 + threadIdx.x;           // f32x4 index
    const int c0  = (idx*4) & 63;
    const float inv_n = 1.0f / (float)NTOT;
    f32x4 v = *((f32x4*)X + idx);
    #pragma unroll
    for (int u = 0; u < 4; ++u) {
        int col = c0 + u;
        float mu  = stats[col] * inv_n;
        float var = stats[64 + col] * inv_n - mu*mu;
        float x   = gamma[col] * (v[u] - mu) / sqrtf(var + EPSV) + beta[col];
        v[u] = fmaxf(x, 0.0f);
    }
    *((f32x4*)X + idx) = v;
}

extern "C" void kernel_launch(void* const* d_in, const int* in_sizes, int n_in,
                              void* d_out, int out_size, void* d_ws, size_t ws_size,
                              hipStream_t stream)
{
    const float* h     = (const float*)d_in[0];
    // d_in[1] seq_start_end: provably uniform (reference only uses N//nseq)
    const float* pos   = (const float*)d_in[2];
    const float* W     = (const float*)d_in[3];
    const float* bvec  = (const float*)d_in[4];
    const float* gamma = (const float*)d_in[5];
    const float* beta  = (const float*)d_in[6];

    float* X        = (float*)d_out;
    short* Wt       = (short*)d_ws;                           // 512 KB bf16 W^T
    float* partials = (float*)((char*)d_ws + 524288);         // 128*256*4 = 128 KB
    float* stats    = (float*)((char*)d_ws + 524288 + 131072);// 512 B

    sp_transpose<<<64,  256, 0, stream>>>(W, Wt);
    sp_main    <<<NSEQ, 256, 0, stream>>>(h, pos, Wt, bvec, X, partials);
    sp_reduce  <<<128,  64,  0, stream>>>(partials, stats);
    sp_norm    <<<(NTOT*HD/4)/256, 256, 0, stream>>>(X, stats, gamma, beta);
}